// Round 3
// baseline (214.930 us; speedup 1.0000x reference)
//
#include <hip/hip_runtime.h>
#include <hip/hip_bf16.h>
#include <math.h>

typedef float f32x4 __attribute__((ext_vector_type(4)));
typedef __bf16 bf16x8 __attribute__((ext_vector_type(8)));

#define PI2 6.283185307179586

static __device__ __forceinline__ unsigned short f2b(float f) {
  __hip_bfloat16 h = __float2bfloat16(f);
  return reinterpret_cast<unsigned short&>(h);
}

// ---------------- setup: pos table (padded [64][36]) + twiddle tables ----------------
__global__ __launch_bounds__(256) void setup_tables_kernel(
    int* __restrict__ post, __hip_bfloat16* __restrict__ Tt,
    __hip_bfloat16* __restrict__ Ub) {
  const int tid = threadIdx.x;
  __shared__ int cnt[64];
  __shared__ int pref[64];

  if (tid < 64) {
    int i = tid;
    double ys = -1.0 + (double)i * (2.0 / 63.0);
    int cRow = 0;
    for (int j = 0; j < 33; ++j) {
      double xs = (double)j / 32.0;
      bool m = (fabs(xs) < 0.1) || (fabs(ys) < 0.1) || (xs * xs + ys * ys <= 0.16);
      cRow += m ? 1 : 0;
    }
    cnt[i] = cRow;
  }
  __syncthreads();
  if (tid == 0) {
    int s = 0;
    for (int i = 0; i < 64; ++i) { pref[i] = s; s += cnt[i]; }
  }
  __syncthreads();
  if (tid < 64) {
    int i = tid;
    int k = pref[i];
    double ys = -1.0 + (double)i * (2.0 / 63.0);
    for (int j = 0; j < 36; ++j) {
      int v = -1;
      if (j < 33) {
        double xs = (double)j / 32.0;
        bool m = (fabs(xs) < 0.1) || (fabs(ys) < 0.1) || (xs * xs + ys * ys <= 0.16);
        if (m) v = k++;
      }
      post[i * 36 + j] = v;
    }
  }

  // Tt[80][64]: rows 0..32 = cos(2*pi*n*w/64), rows 40..72 = -sin, else 0
  for (int idx = tid; idx < 80 * 64; idx += 256) {
    int n = idx >> 6, w = idx & 63;
    float v = 0.0f;
    if (n < 33) {
      int r = (n * w) & 63;
      v = cosf((float)(PI2 / 64.0) * (float)r);
    } else if (n >= 40 && n < 73) {
      int r = ((n - 40) * w) & 63;
      v = -sinf((float)(PI2 / 64.0) * (float)r);
    }
    Tt[idx] = __float2bfloat16(v);
  }

  // Ub[128][128]: row u'=u   : [cos | sin], row u'=64+u : [-sin | cos], v=(u+32)&63
  for (int idx = tid; idx < 128 * 128; idx += 256) {
    int up = idx >> 7, kk = idx & 127;
    int u = up & 63;
    int vfreq = (u + 32) & 63;
    int h = kk & 63;
    int r = (vfreq * h) & 63;
    float cv, sv;
    __sincosf((float)(PI2 / 64.0) * (float)r, &sv, &cv);
    float val;
    if (up < 64) val = (kk < 64) ? cv : sv;
    else         val = (kk < 64) ? -sv : cv;
    Ub[idx] = __float2bfloat16(val);
  }
}

// ---------------- weight fp32 -> bf16, K-padded (B^T layout) ----------------
__global__ __launch_bounds__(256) void wconv_kernel(
    const float* __restrict__ W, __hip_bfloat16* __restrict__ wB,
    int N, int Kd, int Kp) {
  int total = N * Kp;
  for (int idx = blockIdx.x * 256 + threadIdx.x; idx < total; idx += gridDim.x * 256) {
    int e = idx / Kp;
    int f = idx - e * Kp;
    float v = (f < Kd) ? W[(size_t)e * Kd + f] : 0.0f;
    wB[idx] = __float2bfloat16(v);
  }
}

// ---------------- fused MFMA rfft2 + fftshift + gather: 1 wave = 1 image ----------------
// WBUF shrunk 12544 -> 8704: Sout holds only 34 rows (33 live + 1 clamp row);
// stage-2 A-fragment rows >33 are clamped to row 33 (their outputs are discarded,
// matmul rows are independent). 4*8704 = 34816 B/block -> 4 blocks/CU -> 16 waves/CU.
#define WAVES 4
#define WBUF 8704   // per-wave LDS bytes (union: Xbf 8192 / Sout 34*256 / featbuf 2176)

__global__ __launch_bounds__(256) void fft_mfma_kernel(
    const float* __restrict__ x,
    const __hip_bfloat16* __restrict__ Tt,   // [80][64]
    const __hip_bfloat16* __restrict__ Ub,   // [128][128]
    const int* __restrict__ post,            // [64][36]
    __hip_bfloat16* __restrict__ feats,
    int K, int Kp) {
  __shared__ __align__(16) char lds[WAVES * WBUF];
  const int tid = threadIdx.x;
  const int lane = tid & 63;
  const int w = tid >> 6;
  const int l4 = lane & 15;
  const int q = lane >> 4;
  const int img = blockIdx.x * WAVES + w;
  const int sp = img / 3;
  const int c = img - sp * 3;
  char* buf = lds + w * WBUF;

  // ---- phase A: load image (fp32) -> bf16 -> LDS Xbf [64][64], XOR-swizzled groups of 8
  {
    const float* xi = x + (size_t)img * 4096;
    #pragma unroll
    for (int i = 0; i < 16; ++i) {
      float4 v = *reinterpret_cast<const float4*>(xi + i * 256 + lane * 4);
      int h = i * 4 + q;
      int k = l4 * 4;
      int off = h * 128 + (((k >> 3) ^ (h & 7)) * 16 + (k & 7) * 2);
      ushort4 b;
      b.x = f2b(v.x); b.y = f2b(v.y); b.z = f2b(v.z); b.w = f2b(v.w);
      *reinterpret_cast<ushort4*>(buf + off) = b;
    }
  }

  // ---- phase B: stage 1 MFMA  S[64][80] = X[64][64] * Tt^T
  f32x4 acc1[4][5] = {};
  #pragma unroll
  for (int ks = 0; ks < 2; ++ks) {
    bf16x8 a1[4], b1[5];
    #pragma unroll
    for (int m = 0; m < 4; ++m) {
      int h = m * 16 + l4;
      int kg = ks * 4 + q;
      a1[m] = *reinterpret_cast<const bf16x8*>(buf + h * 128 + ((kg ^ (h & 7)) * 16));
    }
    #pragma unroll
    for (int n = 0; n < 5; ++n) {
      int row = n * 16 + l4;
      b1[n] = *reinterpret_cast<const bf16x8*>(
          (const char*)Tt + row * 128 + ks * 64 + q * 16);
    }
    #pragma unroll
    for (int m = 0; m < 4; ++m)
      #pragma unroll
      for (int n = 0; n < 5; ++n)
        acc1[m][n] = __builtin_amdgcn_mfma_f32_16x16x32_bf16(a1[m], b1[n], acc1[m][n], 0, 0, 0);
  }

  // ---- phase C: write Sout[j<33][kk<128] (Re at kk=h, Im at kk=64+h), XOR-swizzled
  #pragma unroll
  for (int n = 0; n < 5; ++n) {
    int col = n * 16 + l4;
    bool isRe = (col < 33);
    bool isIm = (col >= 40 && col < 73);
    if (!(isRe || isIm)) continue;
    int j = isRe ? col : (col - 40);
    #pragma unroll
    for (int m = 0; m < 4; ++m) {
      #pragma unroll
      for (int r = 0; r < 4; ++r) {
        int h = m * 16 + q * 4 + r;
        int kk = isRe ? h : (h + 64);
        int off = j * 256 + (((kk >> 3) ^ (j & 15)) * 16 + (kk & 7) * 2);
        *reinterpret_cast<unsigned short*>(buf + off) = f2b(acc1[m][n][r]);
      }
    }
  }

  // ---- phase D: stage 2 MFMA  C2[48][128] = Sout[48][128] * Ub^T
  // A-rows >33 clamped to row 33 (garbage in -> garbage out on discarded rows only)
  f32x4 acc2[3][8] = {};
  #pragma unroll
  for (int ks = 0; ks < 4; ++ks) {
    bf16x8 a2[3], b2[8];
    #pragma unroll
    for (int m = 0; m < 3; ++m) {
      int j = m * 16 + l4;
      if (j > 33) j = 33;                      // clamp: keep LDS reads in 34-row buffer
      int kg = ks * 4 + q;
      a2[m] = *reinterpret_cast<const bf16x8*>(buf + j * 256 + ((kg ^ (j & 15)) * 16));
    }
    #pragma unroll
    for (int n = 0; n < 8; ++n) {
      int row = n * 16 + l4;
      b2[n] = *reinterpret_cast<const bf16x8*>(
          (const char*)Ub + row * 256 + ks * 64 + q * 16);
    }
    #pragma unroll
    for (int m = 0; m < 3; ++m)
      #pragma unroll
      for (int n = 0; n < 8; ++n)
        acc2[m][n] = __builtin_amdgcn_mfma_f32_16x16x32_bf16(a2[m], b2[n], acc2[m][n], 0, 0, 0);
  }

  // ---- phase E: masked gather -> featbuf LDS (Re at [0..K), Im at [K..2K)), bf16
  #pragma unroll
  for (int n = 0; n < 8; ++n) {
    int up = n * 16 + l4;       // u' 0..127
    int u = up & 63;
    int base = (up >> 6) ? K : 0;
    #pragma unroll
    for (int m = 0; m < 3; ++m) {
      int j0 = m * 16 + q * 4;
      if (j0 >= 33) continue;
      int4 kv = *reinterpret_cast<const int4*>(post + u * 36 + j0);
      #pragma unroll
      for (int r = 0; r < 4; ++r) {
        int j = j0 + r;
        int k = (&kv.x)[r];
        if (j < 33 && k >= 0)
          *reinterpret_cast<unsigned short*>(buf + (base + k) * 2) = f2b(acc2[m][n][r]);
      }
    }
  }

  // ---- copy featbuf -> feats (two contiguous dword runs) + zero K-pad (c==2 wave)
  {
    size_t obase = (size_t)sp * Kp;
    const unsigned int* fb = reinterpret_cast<const unsigned int*>(buf);
    unsigned int* gRe = reinterpret_cast<unsigned int*>(feats + obase + (size_t)c * K);
    unsigned int* gIm = reinterpret_cast<unsigned int*>(feats + obase + (size_t)3 * K + (size_t)c * K);
    const int KD2 = K / 2;   // 271 dwords per run
    for (int i = lane; i < KD2; i += 64) {
      gRe[i] = fb[i];
      gIm[i] = fb[KD2 + i];
    }
    if (c == 2) {
      unsigned int* gp = reinterpret_cast<unsigned int*>(feats + obase + (size_t)6 * K);
      int padDw = (Kp - 6 * K) / 2;
      for (int i = lane; i < padDw; i += 64) gp[i] = 0u;
    }
  }
}

// ---------------- bf16 MFMA GEMM: out[M][N] = A[M][Kp] * B[N][Kp]^T + bias ----------------
#define BM 128
#define BN 128
#define BKK 64

__global__ __launch_bounds__(256) void gemm_bias_kernel(
    const __hip_bfloat16* __restrict__ A, const __hip_bfloat16* __restrict__ B,
    const float* __restrict__ bias, float* __restrict__ C,
    int M, int N, int Kp) {
  __shared__ __align__(16) unsigned short As[BM * BKK];
  __shared__ __align__(16) unsigned short Bs[BN * BKK];

  const int tid = threadIdx.x;
  const int lane = tid & 63;
  const int wid = tid >> 6;
  const int wm = wid & 1;
  const int wn = wid >> 1;
  const int nbm = M / BM;
  const int bm = blockIdx.x % nbm;
  const int bn = blockIdx.x / nbm;
  const int row0A = bm * BM;
  const int row0B = bn * BN;

  f32x4 acc[4][4] = {};

  for (int k0 = 0; k0 < Kp; k0 += BKK) {
    #pragma unroll
    for (int i = 0; i < 4; ++i) {
      int qc = i * 256 + tid;
      int r = qc >> 3;
      int cb = (qc & 7) * 16;
      const char* gA = (const char*)A + ((size_t)(row0A + r) * Kp + k0) * 2 + cb;
      const char* gB = (const char*)B + ((size_t)(row0B + r) * Kp + k0) * 2 + cb;
      char* lA = (char*)As + (size_t)(i * 256 + wid * 64) * 16;
      char* lB = (char*)Bs + (size_t)(i * 256 + wid * 64) * 16;
      __builtin_amdgcn_global_load_lds((const __attribute__((address_space(1))) void*)gA,
                                       (__attribute__((address_space(3))) void*)lA, 16, 0, 0);
      __builtin_amdgcn_global_load_lds((const __attribute__((address_space(1))) void*)gB,
                                       (__attribute__((address_space(3))) void*)lB, 16, 0, 0);
    }
    __syncthreads();

    #pragma unroll
    for (int kk = 0; kk < 2; ++kk) {
      bf16x8 afr[4], bfr[4];
      const int ke = kk * 32 + (lane >> 4) * 8;
      #pragma unroll
      for (int m = 0; m < 4; ++m) {
        int rowA = wm * 64 + m * 16 + (lane & 15);
        afr[m] = *reinterpret_cast<const bf16x8*>(&As[rowA * BKK + ke]);
      }
      #pragma unroll
      for (int n = 0; n < 4; ++n) {
        int rowB = wn * 64 + n * 16 + (lane & 15);
        bfr[n] = *reinterpret_cast<const bf16x8*>(&Bs[rowB * BKK + ke]);
      }
      #pragma unroll
      for (int m = 0; m < 4; ++m)
        #pragma unroll
        for (int n = 0; n < 4; ++n)
          acc[m][n] = __builtin_amdgcn_mfma_f32_16x16x32_bf16(afr[m], bfr[n], acc[m][n], 0, 0, 0);
    }
    __syncthreads();
  }

  #pragma unroll
  for (int n = 0; n < 4; ++n) {
    int gcol = row0B + wn * 64 + n * 16 + (lane & 15);
    float bv = bias[gcol];
    #pragma unroll
    for (int m = 0; m < 4; ++m) {
      int grow0 = row0A + wm * 64 + m * 16 + (lane >> 4) * 4;
      #pragma unroll
      for (int r = 0; r < 4; ++r) {
        C[(size_t)(grow0 + r) * N + gcol] = acc[m][n][r] + bv;
      }
    }
  }
}

extern "C" void kernel_launch(void* const* d_in, const int* in_sizes, int n_in,
                              void* d_out, int out_size, void* d_ws, size_t ws_size,
                              hipStream_t stream) {
  const float* x = (const float*)d_in[0];
  const float* W = (const float*)d_in[2];
  const float* bias = (const float*)d_in[3];
  float* out = (float*)d_out;

  const int ENC = in_sizes[3];                 // 1024
  const int Kd = in_sizes[2] / ENC;            // 6*K = 3252
  const int K = Kd / 6;                        // 542
  const int NIMG = in_sizes[0] / 4096;         // 12288
  const int SP = NIMG / 3;                     // 4096
  const int Kp = (Kd + 63) & ~63;              // 3264

  char* ws = (char*)d_ws;
  int* post = (int*)ws;                                    // 64*36*4 = 9216
  __hip_bfloat16* Tt = (__hip_bfloat16*)(ws + 9216);       // 80*64*2 = 10240
  __hip_bfloat16* Ub = (__hip_bfloat16*)(ws + 19456);      // 128*128*2 = 32768
  __hip_bfloat16* wB = (__hip_bfloat16*)(ws + 52224);      // ENC*Kp*2
  size_t wBytes = (size_t)ENC * Kp * 2;
  __hip_bfloat16* feats = (__hip_bfloat16*)(ws + 52224 + wBytes);

  setup_tables_kernel<<<1, 256, 0, stream>>>(post, Tt, Ub);
  wconv_kernel<<<1024, 256, 0, stream>>>(W, wB, ENC, Kd, Kp);
  fft_mfma_kernel<<<NIMG / WAVES, 256, 0, stream>>>(x, Tt, Ub, post, feats, K, Kp);
  gemm_bias_kernel<<<(SP / BM) * (ENC / BN), 256, 0, stream>>>(feats, wB, bias, out, SP, ENC, Kp);
}

// Round 4
// 189.033 us; speedup vs baseline: 1.1370x; 1.1370x over previous
//
#include <hip/hip_runtime.h>
#include <hip/hip_bf16.h>
#include <math.h>

typedef float f32x4 __attribute__((ext_vector_type(4)));
typedef __bf16 bf16x8 __attribute__((ext_vector_type(8)));

#define PI2 6.283185307179586

static __device__ __forceinline__ unsigned short f2b(float f) {
  __hip_bfloat16 h = __float2bfloat16(f);
  return reinterpret_cast<unsigned short&>(h);
}

// ---------------- setup: pos table (ushort [64][36]) + twiddle tables ----------------
__global__ __launch_bounds__(256) void setup_tables_kernel(
    unsigned short* __restrict__ post16, __hip_bfloat16* __restrict__ Tt,
    __hip_bfloat16* __restrict__ Ub) {
  const int tid = threadIdx.x;
  __shared__ int cnt[64];
  __shared__ int pref[64];

  if (tid < 64) {
    int i = tid;
    double ys = -1.0 + (double)i * (2.0 / 63.0);
    int cRow = 0;
    for (int j = 0; j < 33; ++j) {
      double xs = (double)j / 32.0;
      bool m = (fabs(xs) < 0.1) || (fabs(ys) < 0.1) || (xs * xs + ys * ys <= 0.16);
      cRow += m ? 1 : 0;
    }
    cnt[i] = cRow;
  }
  __syncthreads();
  if (tid == 0) {
    int s = 0;
    for (int i = 0; i < 64; ++i) { pref[i] = s; s += cnt[i]; }
  }
  __syncthreads();
  if (tid < 64) {
    int i = tid;
    int k = pref[i];
    double ys = -1.0 + (double)i * (2.0 / 63.0);
    for (int j = 0; j < 36; ++j) {
      unsigned short v = 0xFFFFu;
      if (j < 33) {
        double xs = (double)j / 32.0;
        bool m = (fabs(xs) < 0.1) || (fabs(ys) < 0.1) || (xs * xs + ys * ys <= 0.16);
        if (m) v = (unsigned short)(k++);
      }
      post16[i * 36 + j] = v;
    }
  }

  // Tt[80][64]: rows 0..32 = cos(2*pi*n*w/64), rows 40..72 = -sin, else 0
  for (int idx = tid; idx < 80 * 64; idx += 256) {
    int n = idx >> 6, w = idx & 63;
    float v = 0.0f;
    if (n < 33) {
      int r = (n * w) & 63;
      v = cosf((float)(PI2 / 64.0) * (float)r);
    } else if (n >= 40 && n < 73) {
      int r = ((n - 40) * w) & 63;
      v = -sinf((float)(PI2 / 64.0) * (float)r);
    }
    Tt[idx] = __float2bfloat16(v);
  }

  // Ub[128][128]: row u'=u   : [cos | sin], row u'=64+u : [-sin | cos], v=(u+32)&63
  for (int idx = tid; idx < 128 * 128; idx += 256) {
    int up = idx >> 7, kk = idx & 127;
    int u = up & 63;
    int vfreq = (u + 32) & 63;
    int h = kk & 63;
    int r = (vfreq * h) & 63;
    float cv, sv;
    __sincosf((float)(PI2 / 64.0) * (float)r, &sv, &cv);
    float val;
    if (up < 64) val = (kk < 64) ? cv : sv;
    else         val = (kk < 64) ? -sv : cv;
    Ub[idx] = __float2bfloat16(val);
  }
}

// ---------------- weight fp32 -> bf16, K-padded (B^T layout) ----------------
__global__ __launch_bounds__(256) void wconv_kernel(
    const float* __restrict__ W, __hip_bfloat16* __restrict__ wB,
    int N, int Kd, int Kp) {
  int total = N * Kp;
  for (int idx = blockIdx.x * 256 + threadIdx.x; idx < total; idx += gridDim.x * 256) {
    int e = idx / Kp;
    int f = idx - e * Kp;
    float v = (f < Kd) ? W[(size_t)e * Kd + f] : 0.0f;
    wB[idx] = __float2bfloat16(v);
  }
}

// ---------------- fused MFMA rfft2 + fftshift + gather: 1 wave = 1 image ----------------
// Phase A now: 16x global_load_lds (async, one vmcnt drain at the block barrier),
// then in-place LDS fp32->bf16 conversion (round r reads [1024r,1024r+1024),
// writes [512r,512r+512) -- strictly below the read frontier, so safe).
// WBUF = 16384 (fp32 staging; bf16 X / Sout / featbuf all alias below it).
// post table lives in block-shared LDS (ushort, 4608 B), loaded co-op once.
#define WAVES 2
#define WBUF 16384
#define POSTB 4608

__global__ __launch_bounds__(128) void fft_mfma_kernel(
    const float* __restrict__ x,
    const __hip_bfloat16* __restrict__ Tt,   // [80][64]
    const __hip_bfloat16* __restrict__ Ub,   // [128][128]
    const unsigned short* __restrict__ post16, // [64][36]
    __hip_bfloat16* __restrict__ feats,
    int K, int Kp) {
  __shared__ __align__(16) char lds[WAVES * WBUF + POSTB];
  const int tid = threadIdx.x;
  const int lane = tid & 63;
  const int w = tid >> 6;
  const int l4 = lane & 15;
  const int q = lane >> 4;
  const int img = blockIdx.x * WAVES + w;
  const int sp = img / 3;
  const int c = img - sp * 3;
  char* buf = lds + w * WBUF;
  unsigned short* postl = reinterpret_cast<unsigned short*>(lds + WAVES * WBUF);

  // ---- phase A1: issue 16 async 1KB row-group loads (fp32, linear) ----
  {
    const float* xi = x + (size_t)img * 4096;
    #pragma unroll
    for (int r = 0; r < 16; ++r) {
      const float* g = xi + r * 256 + lane * 4;
      __builtin_amdgcn_global_load_lds(
          (const __attribute__((address_space(1))) void*)g,
          (__attribute__((address_space(3))) void*)(buf + r * 1024), 16, 0, 0);
    }
  }
  // ---- co-op: load post16 into LDS (1152 dwords) ----
  {
    const unsigned int* src = reinterpret_cast<const unsigned int*>(post16);
    unsigned int* dst = reinterpret_cast<unsigned int*>(postl);
    for (int i = tid; i < (64 * 36) / 2; i += 128) dst[i] = src[i];
  }
  asm volatile("s_waitcnt vmcnt(0)" ::: "memory");
  __syncthreads();   // drains vmcnt/lgkmcnt; post16 + image staging now visible

  // ---- phase A2: in-place fp32 -> bf16 conversion, XOR-swizzled rows ----
  #pragma unroll
  for (int r = 0; r < 16; ++r) {
    float4 v = *reinterpret_cast<const float4*>(buf + r * 1024 + lane * 16);
    int h = r * 4 + (lane >> 4);
    int woff = h * 128 + (((l4 >> 1) ^ (h & 7)) * 16 + (l4 & 1) * 8);
    ushort4 b;
    b.x = f2b(v.x); b.y = f2b(v.y); b.z = f2b(v.z); b.w = f2b(v.w);
    *reinterpret_cast<ushort4*>(buf + woff) = b;
  }

  // ---- phase B: stage 1 MFMA  S[64][80] = X[64][64] * Tt^T
  f32x4 acc1[4][5] = {};
  #pragma unroll
  for (int ks = 0; ks < 2; ++ks) {
    bf16x8 a1[4], b1[5];
    #pragma unroll
    for (int m = 0; m < 4; ++m) {
      int h = m * 16 + l4;
      int kg = ks * 4 + q;
      a1[m] = *reinterpret_cast<const bf16x8*>(buf + h * 128 + ((kg ^ (h & 7)) * 16));
    }
    #pragma unroll
    for (int n = 0; n < 5; ++n) {
      int row = n * 16 + l4;
      b1[n] = *reinterpret_cast<const bf16x8*>(
          (const char*)Tt + row * 128 + ks * 64 + q * 16);
    }
    #pragma unroll
    for (int m = 0; m < 4; ++m)
      #pragma unroll
      for (int n = 0; n < 5; ++n)
        acc1[m][n] = __builtin_amdgcn_mfma_f32_16x16x32_bf16(a1[m], b1[n], acc1[m][n], 0, 0, 0);
  }

  // ---- phase C: write Sout[j<33][kk<128] (Re at kk=h, Im at kk=64+h), XOR-swizzled
  #pragma unroll
  for (int n = 0; n < 5; ++n) {
    int col = n * 16 + l4;
    bool isRe = (col < 33);
    bool isIm = (col >= 40 && col < 73);
    if (!(isRe || isIm)) continue;
    int j = isRe ? col : (col - 40);
    #pragma unroll
    for (int m = 0; m < 4; ++m) {
      #pragma unroll
      for (int r = 0; r < 4; ++r) {
        int h = m * 16 + q * 4 + r;
        int kk = isRe ? h : (h + 64);
        int off = j * 256 + (((kk >> 3) ^ (j & 15)) * 16 + (kk & 7) * 2);
        *reinterpret_cast<unsigned short*>(buf + off) = f2b(acc1[m][n][r]);
      }
    }
  }

  // ---- phase D: stage 2 MFMA  C2[48][128] = Sout[48][128] * Ub^T
  // A-rows >33 clamped to row 33 (their outputs are discarded; rows independent)
  f32x4 acc2[3][8] = {};
  #pragma unroll
  for (int ks = 0; ks < 4; ++ks) {
    bf16x8 a2[3], b2[8];
    #pragma unroll
    for (int m = 0; m < 3; ++m) {
      int j = m * 16 + l4;
      if (j > 33) j = 33;
      int kg = ks * 4 + q;
      a2[m] = *reinterpret_cast<const bf16x8*>(buf + j * 256 + ((kg ^ (j & 15)) * 16));
    }
    #pragma unroll
    for (int n = 0; n < 8; ++n) {
      int row = n * 16 + l4;
      b2[n] = *reinterpret_cast<const bf16x8*>(
          (const char*)Ub + row * 256 + ks * 64 + q * 16);
    }
    #pragma unroll
    for (int m = 0; m < 3; ++m)
      #pragma unroll
      for (int n = 0; n < 8; ++n)
        acc2[m][n] = __builtin_amdgcn_mfma_f32_16x16x32_bf16(a2[m], b2[n], acc2[m][n], 0, 0, 0);
  }

  // ---- phase E: masked gather -> featbuf LDS (Re at [0..K), Im at [K..2K)), bf16
  #pragma unroll
  for (int n = 0; n < 8; ++n) {
    int up = n * 16 + l4;       // u' 0..127
    int u = up & 63;
    int base = (up >> 6) ? K : 0;
    #pragma unroll
    for (int m = 0; m < 3; ++m) {
      int j0 = m * 16 + q * 4;
      if (j0 >= 33) continue;
      ushort4 kv = *reinterpret_cast<const ushort4*>(postl + u * 36 + j0);
      #pragma unroll
      for (int r = 0; r < 4; ++r) {
        int j = j0 + r;
        short k = (short)((&kv.x)[r]);
        if (j < 33 && k >= 0)
          *reinterpret_cast<unsigned short*>(buf + ((int)k + base) * 2) = f2b(acc2[m][n][r]);
      }
    }
  }

  // ---- copy featbuf -> feats (two contiguous dword runs) + zero K-pad (c==2 wave)
  {
    size_t obase = (size_t)sp * Kp;
    const unsigned int* fb = reinterpret_cast<const unsigned int*>(buf);
    unsigned int* gRe = reinterpret_cast<unsigned int*>(feats + obase + (size_t)c * K);
    unsigned int* gIm = reinterpret_cast<unsigned int*>(feats + obase + (size_t)3 * K + (size_t)c * K);
    const int KD2 = K / 2;   // 271 dwords per run
    for (int i = lane; i < KD2; i += 64) {
      gRe[i] = fb[i];
      gIm[i] = fb[KD2 + i];
    }
    if (c == 2) {
      unsigned int* gp = reinterpret_cast<unsigned int*>(feats + obase + (size_t)6 * K);
      int padDw = (Kp - 6 * K) / 2;
      for (int i = lane; i < padDw; i += 64) gp[i] = 0u;
    }
  }
}

// ---------------- bf16 MFMA GEMM: out[M][N] = A[M][Kp] * B[N][Kp]^T + bias ----------------
#define BM 128
#define BN 128
#define BKK 64

__global__ __launch_bounds__(256) void gemm_bias_kernel(
    const __hip_bfloat16* __restrict__ A, const __hip_bfloat16* __restrict__ B,
    const float* __restrict__ bias, float* __restrict__ C,
    int M, int N, int Kp) {
  __shared__ __align__(16) unsigned short As[BM * BKK];
  __shared__ __align__(16) unsigned short Bs[BN * BKK];

  const int tid = threadIdx.x;
  const int lane = tid & 63;
  const int wid = tid >> 6;
  const int wm = wid & 1;
  const int wn = wid >> 1;
  const int nbm = M / BM;
  const int bm = blockIdx.x % nbm;
  const int bn = blockIdx.x / nbm;
  const int row0A = bm * BM;
  const int row0B = bn * BN;

  f32x4 acc[4][4] = {};

  for (int k0 = 0; k0 < Kp; k0 += BKK) {
    #pragma unroll
    for (int i = 0; i < 4; ++i) {
      int qc = i * 256 + tid;
      int r = qc >> 3;
      int cb = (qc & 7) * 16;
      const char* gA = (const char*)A + ((size_t)(row0A + r) * Kp + k0) * 2 + cb;
      const char* gB = (const char*)B + ((size_t)(row0B + r) * Kp + k0) * 2 + cb;
      char* lA = (char*)As + (size_t)(i * 256 + wid * 64) * 16;
      char* lB = (char*)Bs + (size_t)(i * 256 + wid * 64) * 16;
      __builtin_amdgcn_global_load_lds((const __attribute__((address_space(1))) void*)gA,
                                       (__attribute__((address_space(3))) void*)lA, 16, 0, 0);
      __builtin_amdgcn_global_load_lds((const __attribute__((address_space(1))) void*)gB,
                                       (__attribute__((address_space(3))) void*)lB, 16, 0, 0);
    }
    __syncthreads();

    #pragma unroll
    for (int kk = 0; kk < 2; ++kk) {
      bf16x8 afr[4], bfr[4];
      const int ke = kk * 32 + (lane >> 4) * 8;
      #pragma unroll
      for (int m = 0; m < 4; ++m) {
        int rowA = wm * 64 + m * 16 + (lane & 15);
        afr[m] = *reinterpret_cast<const bf16x8*>(&As[rowA * BKK + ke]);
      }
      #pragma unroll
      for (int n = 0; n < 4; ++n) {
        int rowB = wn * 64 + n * 16 + (lane & 15);
        bfr[n] = *reinterpret_cast<const bf16x8*>(&Bs[rowB * BKK + ke]);
      }
      #pragma unroll
      for (int m = 0; m < 4; ++m)
        #pragma unroll
        for (int n = 0; n < 4; ++n)
          acc[m][n] = __builtin_amdgcn_mfma_f32_16x16x32_bf16(afr[m], bfr[n], acc[m][n], 0, 0, 0);
    }
    __syncthreads();
  }

  #pragma unroll
  for (int n = 0; n < 4; ++n) {
    int gcol = row0B + wn * 64 + n * 16 + (lane & 15);
    float bv = bias[gcol];
    #pragma unroll
    for (int m = 0; m < 4; ++m) {
      int grow0 = row0A + wm * 64 + m * 16 + (lane >> 4) * 4;
      #pragma unroll
      for (int r = 0; r < 4; ++r) {
        C[(size_t)(grow0 + r) * N + gcol] = acc[m][n][r] + bv;
      }
    }
  }
}

extern "C" void kernel_launch(void* const* d_in, const int* in_sizes, int n_in,
                              void* d_out, int out_size, void* d_ws, size_t ws_size,
                              hipStream_t stream) {
  const float* x = (const float*)d_in[0];
  const float* W = (const float*)d_in[2];
  const float* bias = (const float*)d_in[3];
  float* out = (float*)d_out;

  const int ENC = in_sizes[3];                 // 1024
  const int Kd = in_sizes[2] / ENC;            // 6*K = 3252
  const int K = Kd / 6;                        // 542
  const int NIMG = in_sizes[0] / 4096;         // 12288
  const int SP = NIMG / 3;                     // 4096
  const int Kp = (Kd + 63) & ~63;              // 3264

  char* ws = (char*)d_ws;
  unsigned short* post16 = (unsigned short*)ws;            // 64*36*2 = 4608 (region 9216)
  __hip_bfloat16* Tt = (__hip_bfloat16*)(ws + 9216);       // 80*64*2 = 10240
  __hip_bfloat16* Ub = (__hip_bfloat16*)(ws + 19456);      // 128*128*2 = 32768
  __hip_bfloat16* wB = (__hip_bfloat16*)(ws + 52224);      // ENC*Kp*2
  size_t wBytes = (size_t)ENC * Kp * 2;
  __hip_bfloat16* feats = (__hip_bfloat16*)(ws + 52224 + wBytes);

  setup_tables_kernel<<<1, 256, 0, stream>>>(post16, Tt, Ub);
  wconv_kernel<<<1024, 256, 0, stream>>>(W, wB, ENC, Kd, Kp);
  fft_mfma_kernel<<<NIMG / WAVES, 128, 0, stream>>>(x, Tt, Ub, post16, feats, K, Kp);
  gemm_bias_kernel<<<(SP / BM) * (ENC / BN), 256, 0, stream>>>(feats, wB, bias, out, SP, ENC, Kp);
}